// Round 7
// baseline (2241.113 us; speedup 1.0000x reference)
//
#include <hip/hip_runtime.h>
#include <cstdint>
#include <cstddef>

// Problem constants
#define B_ROWS 16384
#define FEAT   2048
#define FIELD  32
#define KDIM   64
#define NCOLS  2048           // FIELD*KDIM (main quadratic columns)
#define NAUG   2176           // 2048 + 64 (vsum) + 1 (w) + 63 zero-pad = 17*128

using half8   = __attribute__((ext_vector_type(8))) _Float16;
using half4   = __attribute__((ext_vector_type(4))) _Float16;
using floatx4 = __attribute__((ext_vector_type(4))) float;

// Async global->LDS, 16B per lane. LDS dest must be wave-uniform base + lane*16.
__device__ __forceinline__ void load_lds16(const void* g, void* l) {
  __builtin_amdgcn_global_load_lds((const __attribute__((address_space(1))) void*)g,
                                   (__attribute__((address_space(3))) void*)l, 16, 0, 0);
}

// --- prep part 1: x fp32 -> xh fp16 ----------------------------------------
__global__ __launch_bounds__(256) void k_prep_x(const float* __restrict__ x,
                                                _Float16* __restrict__ xh) {
  const int bb = blockIdx.x;
  const int t = threadIdx.x;
  size_t i = ((size_t)bb * 256 + t) * 16;
  float4 v0 = *(const float4*)(x + i);
  float4 v1 = *(const float4*)(x + i + 4);
  float4 v2 = *(const float4*)(x + i + 8);
  float4 v3 = *(const float4*)(x + i + 12);
  half8 h0 = { (_Float16)v0.x, (_Float16)v0.y, (_Float16)v0.z, (_Float16)v0.w,
               (_Float16)v1.x, (_Float16)v1.y, (_Float16)v1.z, (_Float16)v1.w };
  half8 h1 = { (_Float16)v2.x, (_Float16)v2.y, (_Float16)v2.z, (_Float16)v2.w,
               (_Float16)v3.x, (_Float16)v3.y, (_Float16)v3.z, (_Float16)v3.w };
  *(half8*)(xh + i) = h0;
  *(half8*)(xh + i + 8) = h1;
}

// --- prep part 2: v transpose + vsum + w/zero rows + arg zero --------------
__global__ __launch_bounds__(256) void k_prep_v(const float* __restrict__ v,
                                                const float* __restrict__ w,
                                                _Float16* __restrict__ vt,
                                                float* __restrict__ arg) {
  const int bb = blockIdx.x;
  const int t = threadIdx.x;
  if (bb < 1024) {
    __shared__ _Float16 tile[64 * 68];
    const int f0 = (bb >> 5) * 64;
    const int n0 = (bb & 31) * 64;
#pragma unroll
    for (int j = 0; j < 4; ++j) {
      int c = j * 256 + t;
      int row = c >> 4;                           // f local
      int col = (c & 15) * 4;                     // n local
      float4 val = *(const float4*)(v + (size_t)(f0 + row) * NCOLS + n0 + col);
      tile[row * 68 + col + 0] = (_Float16)val.x;
      tile[row * 68 + col + 1] = (_Float16)val.y;
      tile[row * 68 + col + 2] = (_Float16)val.z;
      tile[row * 68 + col + 3] = (_Float16)val.w;
    }
    __syncthreads();
#pragma unroll
    for (int j = 0; j < 4; ++j) {
      int c = j * 256 + t;
      int nl = c >> 4;                            // n local (row of vt)
      int fl = (c & 15) * 4;                      // f local group of 4
      half4 h = { tile[(fl + 0) * 68 + nl], tile[(fl + 1) * 68 + nl],
                  tile[(fl + 2) * 68 + nl], tile[(fl + 3) * 68 + nl] };
      *(half4*)(vt + (size_t)(n0 + nl) * FEAT + f0 + fl) = h;
    }
  } else if (bb < 1536) {
    const int k = t & 63;
    const int f = (bb - 1024) * 4 + (t >> 6);
    float s = 0.f;
#pragma unroll
    for (int si = 0; si < FIELD; ++si) s += v[(size_t)f * NCOLS + si * KDIM + k];
    vt[(size_t)(NCOLS + k) * FEAT + f] = (_Float16)s;
  } else if (bb < 2048) {
    int idx = (bb - 1536) * 256 + t;              // 64*2048 elements
    int r = NCOLS + KDIM + (idx >> 11);           // 2112..2175
    int f = idx & 2047;
    vt[(size_t)r * FEAT + f] = (r == NCOLS + KDIM) ? (_Float16)w[f] : (_Float16)0.f;
  } else {
    arg[(bb - 2048) * 256 + t] = 0.f;
  }
}

// --- fused GEMM + row-reduce epilogue: 256x256 tile, 8-wave ----------------
// R7 = R6 (verified 190us) with LDS halved to 64 KiB -> 2 blocks/CU.
//
// Rationale (R6 counters): steady util 44% and a 75%-utilization grid tail
// (576 blocks at 1/CU = rounds 256+256+64) are both co-residency problems:
// a second resident block overlaps our barrier drains, prologue/epilogue
// and tail bubbles (m114 MFMA/VALU co-scheduling). LDS <= 80 KiB is the
// requirement; we hit 64 KiB by SINGLE-buffering the four 16 KiB segments
// (A-kg0, A-kg1, B-kg0, B-kg1) with a rotating restage schedule:
//   per step t (4 phases, R1's verified 2-barrier phase skeleton):
//     ph0: read B0,A0-lo;  stage A1(t)     (A1 drained at ph3(t-1) TAIL)
//     ph1: read A0-hi;     stage B0(t+1)   (B0 drained at ph0 TAIL)
//     ph2: read B1,A1-lo;  stage A0(t+1)   (A0 drained at ph1 TAIL)
//     ph3: read A1-hi;     stage B1(t+1)   (B1 drained at ph2 TAIL)
//   FIFO waits (counted, never 0 in steady):
//     end-ph1: vmcnt(2)  -> B1(t),A1(t) landed   (leaves B0(t+1) in flight)
//     end-ph3: vmcnt(2)  -> B0(t+1),A0(t+1) landed (leaves B1(t+1))
//   WAR: every restage issues after the barrier following its readers'
//   lgkmcnt(0) drain (same proof as R1, HW-verified).  Stage->wait
//   distance >= 1.5 phases; residual latency covered by the co-block.
//
// Granule layout, swizzle, grid mapping (3-n-chunk XCD, bijective 576=8*72),
// epilogue: byte-identical to R6.
__global__ __launch_bounds__(512, 4) void k_gemm(const _Float16* __restrict__ xh,
                                                 const _Float16* __restrict__ vt,
                                                 float* __restrict__ arg) {
  __shared__ __align__(16) _Float16 lds[32768];   // 64 KiB: A0|A1|B0|B1
  const int tid  = threadIdx.x;
  const int lane = tid & 63;
  const int wave = tid >> 6;      // 0..7
  const int wm   = wave >> 2;     // 0..1 -> M offset wm*128
  const int wn   = wave & 3;      // 0..3 -> N offset wn*64
  const int lr   = lane & 15;     // frag row (A) / col (B)
  const int q    = lane >> 4;     // k-chunk within 32-k granule

  // XCD swizzle (576 = 8*72, bijective) + 3-n-chunk decode:
  // wg = ng*192 + mi*3 + nr;  n = ng*3 + nr, m = mi.
  const int bid = blockIdx.x;
  const int wg  = (bid & 7) * 72 + (bid >> 3);
  const int ng  = wg / 192;
  const int rem = wg - ng * 192;
  const int mi  = rem / 3;
  const int nr  = rem - mi * 3;
  const int m0  = mi * 256;
  const int n0  = (ng * 3 + nr) * 256;           // 0..2048

  // segment bases (halves)
  const int SEG_A0 = 0, SEG_A1 = 8192, SEG_B0 = 16384, SEG_B1 = 24576;

  // fragment LDS offsets (halves) within any granule segment.
  // offA[f]+4096 gives the high half (L jumps by 64, slot unchanged: 64&7==0).
  int offA[4], offB[4];
#pragma unroll
  for (int f = 0; f < 4; ++f) {
    int L = f * 16 + lr;
    int u = wm * 4 + q;
    offA[f] = L * 64 + ((u ^ (L & 7)) * 8);
  }
#pragma unroll
  for (int g = 0; g < 4; ++g) {
    int L = (wn & 1) * 64 + g * 16 + lr;
    int u = (wn >> 1) * 4 + q;
    offB[g] = L * 64 + ((u ^ (L & 7)) * 8);
  }

  // staging source decode: linear chunk tid -> (row, kc); dest+4096 -> row+64.
  const int L0   = tid >> 3;
  const int u0   = (tid & 7) ^ (L0 & 7);
  const int row0 = (u0 >> 2) * 128 + L0;
  const int kc0  = u0 & 3;
  const _Float16* pA0 = xh + (size_t)(m0 + row0) * FEAT + kc0 * 8;
  const _Float16* pA1 = pA0 + (size_t)64 * FEAT;
  const int rb0 = (n0 + row0      < NAUG) ? n0 + row0      : NAUG - 1;
  const int rb1 = (n0 + row0 + 64 < NAUG) ? n0 + row0 + 64 : NAUG - 1;
  const _Float16* pB0 = vt + (size_t)rb0 * FEAT + kc0 * 8;
  const _Float16* pB1 = vt + (size_t)rb1 * FEAT + kc0 * 8;

  auto stageA = [&](int koff, int seg) {
    load_lds16(pA0 + koff, lds + seg + tid * 8);
    load_lds16(pA1 + koff, lds + seg + 4096 + tid * 8);
  };
  auto stageB = [&](int koff, int seg) {
    load_lds16(pB0 + koff, lds + seg + tid * 8);
    load_lds16(pB1 + koff, lds + seg + 4096 + tid * 8);
  };

  floatx4 acc[8][4] = {};
  half8 af[4], bf[4];

  // prologue: A0(0), B0(0), B1(0); A1(0) arrives via ph0's stage.
  stageA(0, SEG_A0);
  stageB(0, SEG_B0);
  stageB(32, SEG_B1);
  asm volatile("s_waitcnt vmcnt(2)" ::: "memory");  // A0(0),B0(0) landed
  __builtin_amdgcn_s_barrier();

#define PHASE_TAIL()                                        \
    __builtin_amdgcn_s_barrier();                           \
    asm volatile("s_waitcnt lgkmcnt(0)" ::: "memory");      \
    __builtin_amdgcn_sched_barrier(0);                      \
    __builtin_amdgcn_s_setprio(1)

#define PHASE_END()                                         \
    __builtin_amdgcn_s_setprio(0);                          \
    __builtin_amdgcn_s_barrier()

#pragma unroll 2
  for (int t = 0; t < 32; ++t) {
    // ---- phase 0: kg0, M-frags 0-3; stage A1(t) ---------------------------
#pragma unroll
    for (int g = 0; g < 4; ++g) bf[g] = *(const half8*)(lds + SEG_B0 + offB[g]);
#pragma unroll
    for (int f = 0; f < 4; ++f) af[f] = *(const half8*)(lds + SEG_A0 + offA[f]);
    stageA(t * 64 + 32, SEG_A1);
    PHASE_TAIL();
#pragma unroll
    for (int f = 0; f < 4; ++f)
#pragma unroll
      for (int g = 0; g < 4; ++g)
        acc[f][g] = __builtin_amdgcn_mfma_f32_16x16x32_f16(af[f], bf[g],
                                                           acc[f][g], 0, 0, 0);
    PHASE_END();

    // ---- phase 1: kg0, M-frags 4-7 (bf reused); stage B0(t+1) -------------
#pragma unroll
    for (int f = 0; f < 4; ++f) af[f] = *(const half8*)(lds + SEG_A0 + 4096 + offA[f]);
    if (t < 31) stageB((t + 1) * 64, SEG_B0);
    PHASE_TAIL();
#pragma unroll
    for (int f = 0; f < 4; ++f)
#pragma unroll
      for (int g = 0; g < 4; ++g)
        acc[4 + f][g] = __builtin_amdgcn_mfma_f32_16x16x32_f16(af[f], bf[g],
                                                               acc[4 + f][g], 0, 0, 0);
    __builtin_amdgcn_s_setprio(0);
    // need A1(t) and B1(t) landed before ph2 reads; B0(t+1) may stay in flight
    if (t < 31) { asm volatile("s_waitcnt vmcnt(2)" ::: "memory"); }
    else        { asm volatile("s_waitcnt vmcnt(0)" ::: "memory"); }
    __builtin_amdgcn_sched_barrier(0);
    __builtin_amdgcn_s_barrier();

    // ---- phase 2: kg1, M-frags 0-3; stage A0(t+1) -------------------------
#pragma unroll
    for (int g = 0; g < 4; ++g) bf[g] = *(const half8*)(lds + SEG_B1 + offB[g]);
#pragma unroll
    for (int f = 0; f < 4; ++f) af[f] = *(const half8*)(lds + SEG_A1 + offA[f]);
    if (t < 31) stageA((t + 1) * 64, SEG_A0);
    PHASE_TAIL();
#pragma unroll
    for (int f = 0; f < 4; ++f)
#pragma unroll
      for (int g = 0; g < 4; ++g)
        acc[f][g] = __builtin_amdgcn_mfma_f32_16x16x32_f16(af[f], bf[g],
                                                           acc[f][g], 0, 0, 0);
    PHASE_END();

    // ---- phase 3: kg1, M-frags 4-7; stage B1(t+1) -------------------------
#pragma unroll
    for (int f = 0; f < 4; ++f) af[f] = *(const half8*)(lds + SEG_A1 + 4096 + offA[f]);
    if (t < 31) stageB((t + 1) * 64 + 32, SEG_B1);
    PHASE_TAIL();
#pragma unroll
    for (int f = 0; f < 4; ++f)
#pragma unroll
      for (int g = 0; g < 4; ++g)
        acc[4 + f][g] = __builtin_amdgcn_mfma_f32_16x16x32_f16(af[f], bf[g],
                                                               acc[4 + f][g], 0, 0, 0);
    __builtin_amdgcn_s_setprio(0);
    // need B0(t+1), A0(t+1) landed before ph0(t+1); B1(t+1) may stay in flight
    if (t < 31) { asm volatile("s_waitcnt vmcnt(2)" ::: "memory"); }
    __builtin_amdgcn_sched_barrier(0);
    __builtin_amdgcn_s_barrier();
  }
#undef PHASE_TAIL
#undef PHASE_END

  // Epilogue: C/D layout col=lane&15, row=(lane>>4)*4+reg.
  const int cq = lane >> 4;
  const int mrow = m0 + wm * 128;
  const int ncol = n0 + wn * 64;
#pragma unroll
  for (int f = 0; f < 8; ++f) {
#pragma unroll
    for (int r = 0; r < 4; ++r) {
      float contrib = 0.f;
#pragma unroll
      for (int g = 0; g < 4; ++g) {
        int col = ncol + g * 16 + lr;
        float vv = acc[f][g][r];
        float qv = vv * vv;
        if (col < NCOLS)                contrib -= 0.5f * qv;
        else if (col < NCOLS + KDIM)    contrib += 0.5f * qv;
        else if (col == NCOLS + KDIM)   contrib += vv;
      }
      contrib += __shfl_xor(contrib, 1);
      contrib += __shfl_xor(contrib, 2);
      contrib += __shfl_xor(contrib, 4);
      contrib += __shfl_xor(contrib, 8);
      if (lr == 0) atomicAdd(&arg[mrow + f * 16 + cq * 4 + r], contrib);
    }
  }
}

// --- finalize: sigmoid ------------------------------------------------------
__global__ __launch_bounds__(256) void k_fin(const float* __restrict__ arg,
                                             const float* __restrict__ b,
                                             float* __restrict__ out) {
  int i = blockIdx.x * 256 + threadIdx.x;
  float z = arg[i] + b[0];
  out[i] = 1.f / (1.f + __expf(-z));
}

extern "C" void kernel_launch(void* const* d_in, const int* in_sizes, int n_in,
                              void* d_out, int out_size, void* d_ws, size_t ws_size,
                              hipStream_t stream) {
  const float* x = (const float*)d_in[0];   // [16384, 2048]
  const float* w = (const float*)d_in[1];   // [2048]
  const float* b = (const float*)d_in[2];   // scalar
  const float* v = (const float*)d_in[3];   // [2048, 32, 64]
  float* out = (float*)d_out;               // [16384] fp32

  char* ws = (char*)d_ws;
  _Float16* xh  = (_Float16*)ws;                          // 67,108,864 B
  _Float16* vt  = (_Float16*)(ws + 67108864);             //  8,912,896 B
  float*    arg = (float*)(ws + 67108864 + 8912896);      //     65,536 B

  k_prep_x<<<8192, 256, 0, stream>>>(x, xh);
  k_prep_v<<<2112, 256, 0, stream>>>(v, w, vt, arg);
  k_gemm<<<576, 512, 0, stream>>>(xh, vt, arg);
  k_fin<<<64, 256, 0, stream>>>(arg, b, out);
}

// Round 8
// 374.718 us; speedup vs baseline: 5.9808x; 5.9808x over previous
//
#include <hip/hip_runtime.h>
#include <cstdint>
#include <cstddef>

// Problem constants
#define B_ROWS 16384
#define FEAT   2048
#define FIELD  32
#define KDIM   64
#define NCOLS  2048           // FIELD*KDIM (main quadratic columns)
#define NAUG   2176           // 2048 + 64 (vsum) + 1 (w) + 63 zero-pad

using half8   = __attribute__((ext_vector_type(8))) _Float16;
using half4   = __attribute__((ext_vector_type(4))) _Float16;
using floatx4 = __attribute__((ext_vector_type(4))) float;

// Async global->LDS, 16B per lane. LDS dest must be wave-uniform base + lane*16.
__device__ __forceinline__ void load_lds16(const void* g, void* l) {
  __builtin_amdgcn_global_load_lds((const __attribute__((address_space(1))) void*)g,
                                   (__attribute__((address_space(3))) void*)l, 16, 0, 0);
}

// --- prep part 1: x fp32 -> xh fp16 ----------------------------------------
__global__ __launch_bounds__(256) void k_prep_x(const float* __restrict__ x,
                                                _Float16* __restrict__ xh) {
  const int bb = blockIdx.x;
  const int t = threadIdx.x;
  size_t i = ((size_t)bb * 256 + t) * 16;
  float4 v0 = *(const float4*)(x + i);
  float4 v1 = *(const float4*)(x + i + 4);
  float4 v2 = *(const float4*)(x + i + 8);
  float4 v3 = *(const float4*)(x + i + 12);
  half8 h0 = { (_Float16)v0.x, (_Float16)v0.y, (_Float16)v0.z, (_Float16)v0.w,
               (_Float16)v1.x, (_Float16)v1.y, (_Float16)v1.z, (_Float16)v1.w };
  half8 h1 = { (_Float16)v2.x, (_Float16)v2.y, (_Float16)v2.z, (_Float16)v2.w,
               (_Float16)v3.x, (_Float16)v3.y, (_Float16)v3.z, (_Float16)v3.w };
  *(half8*)(xh + i) = h0;
  *(half8*)(xh + i + 8) = h1;
}

// --- prep part 2: v transpose + vsum + w/zero rows + arg zero --------------
__global__ __launch_bounds__(256) void k_prep_v(const float* __restrict__ v,
                                                const float* __restrict__ w,
                                                _Float16* __restrict__ vt,
                                                float* __restrict__ arg) {
  const int bb = blockIdx.x;
  const int t = threadIdx.x;
  if (bb < 1024) {
    __shared__ _Float16 tile[64 * 68];
    const int f0 = (bb >> 5) * 64;
    const int n0 = (bb & 31) * 64;
#pragma unroll
    for (int j = 0; j < 4; ++j) {
      int c = j * 256 + t;
      int row = c >> 4;                           // f local
      int col = (c & 15) * 4;                     // n local
      float4 val = *(const float4*)(v + (size_t)(f0 + row) * NCOLS + n0 + col);
      tile[row * 68 + col + 0] = (_Float16)val.x;
      tile[row * 68 + col + 1] = (_Float16)val.y;
      tile[row * 68 + col + 2] = (_Float16)val.z;
      tile[row * 68 + col + 3] = (_Float16)val.w;
    }
    __syncthreads();
#pragma unroll
    for (int j = 0; j < 4; ++j) {
      int c = j * 256 + t;
      int nl = c >> 4;                            // n local (row of vt)
      int fl = (c & 15) * 4;                      // f local group of 4
      half4 h = { tile[(fl + 0) * 68 + nl], tile[(fl + 1) * 68 + nl],
                  tile[(fl + 2) * 68 + nl], tile[(fl + 3) * 68 + nl] };
      *(half4*)(vt + (size_t)(n0 + nl) * FEAT + f0 + fl) = h;
    }
  } else if (bb < 1536) {
    const int k = t & 63;
    const int f = (bb - 1024) * 4 + (t >> 6);
    float s = 0.f;
#pragma unroll
    for (int si = 0; si < FIELD; ++si) s += v[(size_t)f * NCOLS + si * KDIM + k];
    vt[(size_t)(NCOLS + k) * FEAT + f] = (_Float16)s;
  } else if (bb < 2048) {
    int idx = (bb - 1536) * 256 + t;              // 64*2048 elements
    int r = NCOLS + KDIM + (idx >> 11);           // 2112..2175
    int f = idx & 2047;
    vt[(size_t)r * FEAT + f] = (r == NCOLS + KDIM) ? (_Float16)w[f] : (_Float16)0.f;
  } else {
    arg[(bb - 2048) * 256 + t] = 0.f;
  }
}

// --- main GEMM (cols 0..2047 only) + row-reduce epilogue -------------------
// R8 = R6 verbatim (verified 190us) with the aug n-panel REMOVED: grid
// 512 = 64m x 8n = EXACTLY 2 blocks/CU -> zero grid tail (R6's 3rd round
// was 64 blocks on 256 CUs = 25% loss; aug cols move to k_fin_aug).
// XCD swizzle 512 = 8*64 bijective; 2-n-groups per XCD -> 2MB B L2-hot.
// All cols < 2048 -> epilogue coeff uniformly -0.5*c^2 (branches gone).
// R7 lesson: 256^2 8-wave tile needs the full 512-reg/wave budget
// (launch_bounds(512,2)); forcing 4 waves/SIMD spills acc to scratch.
__global__ __launch_bounds__(512, 2) void k_gemm(const _Float16* __restrict__ xh,
                                                 const _Float16* __restrict__ vt,
                                                 float* __restrict__ arg) {
  __shared__ __align__(16) _Float16 lds[65536];   // 128 KiB
  const int tid  = threadIdx.x;
  const int lane = tid & 63;
  const int wave = tid >> 6;      // 0..7
  const int wm   = wave >> 2;     // 0..1 -> M offset wm*128
  const int wn   = wave & 3;      // 0..3 -> N offset wn*64
  const int lr   = lane & 15;     // frag row (A) / col (B)
  const int q    = lane >> 4;     // k-chunk within 32-k granule

  // XCD swizzle (512 = 8*64, bijective) + 2-n-group decode:
  // wg = ng*128 + mi*2 + nr; n = ng*2 + nr, m = mi. Each XCD: 2 B panels
  // (2MB, L2-resident) x 32 A panels (reused x2 while L2/L3-hot).
  const int bid = blockIdx.x;
  const int wg  = (bid & 7) * 64 + (bid >> 3);
  const int ng  = wg >> 7;
  const int rem = wg & 127;
  const int mi  = rem >> 1;
  const int nr  = rem & 1;
  const int m0  = mi * 256;
  const int n0  = (ng * 2 + nr) * 256;           // 0..1792

  // fragment LDS offsets (halves) within any granule segment.
  int offA[4], offB[4];
#pragma unroll
  for (int f = 0; f < 4; ++f) {
    int L = f * 16 + lr;
    int u = wm * 4 + q;
    offA[f] = L * 64 + ((u ^ (L & 7)) * 8);
  }
#pragma unroll
  for (int g = 0; g < 4; ++g) {
    int L = (wn & 1) * 64 + g * 16 + lr;
    int u = (wn >> 1) * 4 + q;
    offB[g] = L * 64 + ((u ^ (L & 7)) * 8);
  }

  // staging source decode: linear chunk tid -> (row, kc); dest+4096 -> row+64.
  const int L0   = tid >> 3;
  const int u0   = (tid & 7) ^ (L0 & 7);
  const int row0 = (u0 >> 2) * 128 + L0;
  const int kc0  = u0 & 3;
  const _Float16* pA0 = xh + (size_t)(m0 + row0) * FEAT + kc0 * 8;
  const _Float16* pA1 = pA0 + (size_t)64 * FEAT;
  const _Float16* pB0 = vt + (size_t)(n0 + row0) * FEAT + kc0 * 8;  // rows < 2048
  const _Float16* pB1 = pB0 + (size_t)64 * FEAT;

  auto stageA = [&](int koff, int seg) {
    load_lds16(pA0 + koff, lds + seg + tid * 8);
    load_lds16(pA1 + koff, lds + seg + 4096 + tid * 8);
  };
  auto stageB = [&](int koff, int seg) {
    load_lds16(pB0 + koff, lds + seg + tid * 8);
    load_lds16(pB1 + koff, lds + seg + 4096 + tid * 8);
  };

  floatx4 acc[8][4] = {};
  half8 af[4], bf[4];

  // prologue: K-tile 0 (both granules) + K-tile 1 kg0.
  stageA(0, 0);       stageB(0, 32768);
  stageA(32, 8192);   stageB(32, 40960);
  stageA(64, 16384);  stageB(64, 49152);
  asm volatile("s_waitcnt vmcnt(4)" ::: "memory");  // K-tile 0 fully landed
  __builtin_amdgcn_s_barrier();

#define PHASE_TAIL()                                        \
    __builtin_amdgcn_s_barrier();                           \
    asm volatile("s_waitcnt lgkmcnt(0)" ::: "memory");      \
    __builtin_amdgcn_sched_barrier(0);                      \
    __builtin_amdgcn_s_setprio(1)

#define PHASE_END()                                         \
    __builtin_amdgcn_s_setprio(0);                          \
    __builtin_amdgcn_s_barrier()

#pragma unroll 2
  for (int t = 0; t < 32; ++t) {
    const int sA0  = ((t & 1) << 1) * 8192;                 // segA(buf, kg0)
    const int sB0  = 32768 + sA0;                           // segB(buf, kg0)
    const int sPA1 = ((((t + 1) & 1) << 1) | 1) * 8192;     // segA(buf^1, kg1)

    // ---- phase 0: ks=0, M-frags 0-3 ---------------------------------------
#pragma unroll
    for (int g = 0; g < 4; ++g) bf[g] = *(const half8*)(lds + sB0 + offB[g]);
#pragma unroll
    for (int f = 0; f < 4; ++f) af[f] = *(const half8*)(lds + sA0 + offA[f]);
    if (t < 31) stageA((t + 1) * 64 + 32, sPA1);
    PHASE_TAIL();
#pragma unroll
    for (int f = 0; f < 4; ++f)
#pragma unroll
      for (int g = 0; g < 4; ++g)
        acc[f][g] = __builtin_amdgcn_mfma_f32_16x16x32_f16(af[f], bf[g],
                                                           acc[f][g], 0, 0, 0);
    PHASE_END();

    // ---- phase 1: ks=0, M-frags 4-7 (bf reused) ---------------------------
#pragma unroll
    for (int f = 0; f < 4; ++f) af[f] = *(const half8*)(lds + sA0 + 4096 + offA[f]);
    if (t < 31) stageB((t + 1) * 64 + 32, 32768 + sPA1);
    PHASE_TAIL();
#pragma unroll
    for (int f = 0; f < 4; ++f)
#pragma unroll
      for (int g = 0; g < 4; ++g)
        acc[4 + f][g] = __builtin_amdgcn_mfma_f32_16x16x32_f16(af[f], bf[g],
                                                               acc[4 + f][g], 0, 0, 0);
    PHASE_END();

    // ---- phase 2: ks=32, M-frags 0-3 --------------------------------------
#pragma unroll
    for (int g = 0; g < 4; ++g) bf[g] = *(const half8*)(lds + sB0 + 8192 + offB[g]);
#pragma unroll
    for (int f = 0; f < 4; ++f) af[f] = *(const half8*)(lds + sA0 + 8192 + offA[f]);
    if (t < 30) stageA((t + 2) * 64, sA0);
    PHASE_TAIL();
#pragma unroll
    for (int f = 0; f < 4; ++f)
#pragma unroll
      for (int g = 0; g < 4; ++g)
        acc[f][g] = __builtin_amdgcn_mfma_f32_16x16x32_f16(af[f], bf[g],
                                                           acc[f][g], 0, 0, 0);
    PHASE_END();

    // ---- phase 3: ks=32, M-frags 4-7 + per-K-tile counted vmcnt -----------
#pragma unroll
    for (int f = 0; f < 4; ++f) af[f] = *(const half8*)(lds + sA0 + 12288 + offA[f]);
    if (t < 30) stageB((t + 2) * 64, sB0);
    __builtin_amdgcn_s_barrier();
    asm volatile("s_waitcnt lgkmcnt(0)" ::: "memory");
    __builtin_amdgcn_sched_barrier(0);
    __builtin_amdgcn_s_setprio(1);
#pragma unroll
    for (int f = 0; f < 4; ++f)
#pragma unroll
      for (int g = 0; g < 4; ++g)
        acc[4 + f][g] = __builtin_amdgcn_mfma_f32_16x16x32_f16(af[f], bf[g],
                                                               acc[4 + f][g], 0, 0, 0);
    __builtin_amdgcn_s_setprio(0);
    if (t < 30) { asm volatile("s_waitcnt vmcnt(4)" ::: "memory"); }
    else        { asm volatile("s_waitcnt vmcnt(0)" ::: "memory"); }
    __builtin_amdgcn_sched_barrier(0);
    __builtin_amdgcn_s_barrier();
  }
#undef PHASE_TAIL
#undef PHASE_END

  // Epilogue: C/D layout col=lane&15, row=(lane>>4)*4+reg. All cols < 2048
  // -> coeff uniformly -0.5*c^2.
  const int cq = lane >> 4;
  const int mrow = m0 + wm * 128;
#pragma unroll
  for (int f = 0; f < 8; ++f) {
#pragma unroll
    for (int r = 0; r < 4; ++r) {
      float contrib = 0.f;
#pragma unroll
      for (int g = 0; g < 4; ++g) {
        float vv = acc[f][g][r];
        contrib -= 0.5f * vv * vv;
      }
      contrib += __shfl_xor(contrib, 1);
      contrib += __shfl_xor(contrib, 2);
      contrib += __shfl_xor(contrib, 4);
      contrib += __shfl_xor(contrib, 8);
      if (lr == 0) atomicAdd(&arg[mrow + f * 16 + cq * 4 + r], contrib);
    }
  }
}

// --- fused aug thin-GEMM + finalize ----------------------------------------
// Computes per row m: aug = sum_{k<64} 0.5*s_k^2 + x.w  via C_aug = xh * 
// vt[2048..2175]^T (cols: 0..63 vsum -> +0.5c^2, 64 -> +c (w), 65..127 zero),
// then out[m] = sigmoid(arg[m] + aug + b).  BM=64, BN=128, 4 waves,
// R0-verified simple staging skeleton (XOR-swizzled load_lds16 +
// __syncthreads). Grid 256 blocks x 64 rows = 16384.
__global__ __launch_bounds__(256) void k_fin_aug(const _Float16* __restrict__ xh,
                                                 const _Float16* __restrict__ vt,
                                                 const float* __restrict__ arg,
                                                 const float* __restrict__ b,
                                                 float* __restrict__ out) {
  __shared__ __align__(16) _Float16 lds_a[64 * 64];
  __shared__ __align__(16) _Float16 lds_b[128 * 64];
  __shared__ float augp[64];
  const int t = threadIdx.x;
  const int m0 = blockIdx.x * 64;
  const int lane = t & 63;
  const int wave = t >> 6;
  const int wm = (wave & 1) * 32;               // M offset (2 frag rows)
  const int wn = (wave >> 1) * 64;              // N offset (4 frag cols)
  const int lr = lane & 15;
  const int lk = (lane >> 4) * 8;

  if (t < 64) augp[t] = 0.f;

  floatx4 acc[2][4] = {};

  for (int k0 = 0; k0 < FEAT; k0 += 64) {
    // Stage A (64x64) + B (128x64, vt rows 2048..2175), XOR-swizzled.
#pragma unroll
    for (int i = 0; i < 2; ++i) {
      int c = i * 256 + t;                      // 0..511
      int row = c >> 3;
      int g = (c & 7) ^ (row & 7);
      load_lds16(xh + (size_t)(m0 + row) * FEAT + k0 + g * 8, lds_a + c * 8);
    }
#pragma unroll
    for (int i = 0; i < 4; ++i) {
      int c = i * 256 + t;                      // 0..1023
      int row = c >> 3;
      int g = (c & 7) ^ (row & 7);
      load_lds16(vt + (size_t)(NCOLS + row) * FEAT + k0 + g * 8, lds_b + c * 8);
    }
    __syncthreads();
#pragma unroll
    for (int ks = 0; ks < 64; ks += 32) {
      const int kc = (ks + lk) >> 3;
      half8 af[2], bf[4];
#pragma unroll
      for (int f = 0; f < 2; ++f) {
        int ma = wm + f * 16 + lr;
        af[f] = *(const half8*)(lds_a + ma * 64 + (kc ^ (ma & 7)) * 8);
      }
#pragma unroll
      for (int f = 0; f < 4; ++f) {
        int nb = wn + f * 16 + lr;
        bf[f] = *(const half8*)(lds_b + nb * 64 + (kc ^ (nb & 7)) * 8);
      }
#pragma unroll
      for (int fm = 0; fm < 2; ++fm)
#pragma unroll
        for (int fn = 0; fn < 4; ++fn)
          acc[fm][fn] = __builtin_amdgcn_mfma_f32_16x16x32_f16(af[fm], bf[fn],
                                                               acc[fm][fn], 0, 0, 0);
    }
    __syncthreads();
  }

  // Epilogue: aug coeffs. col local: <64 -> +0.5c^2 (vsum), ==64 -> +c (w).
  const int cq = lane >> 4;
#pragma unroll
  for (int fm = 0; fm < 2; ++fm) {
#pragma unroll
    for (int r = 0; r < 4; ++r) {
      float contrib = 0.f;
#pragma unroll
      for (int fn = 0; fn < 4; ++fn) {
        int col = wn + fn * 16 + lr;
        float vv = acc[fm][fn][r];
        if (col < KDIM)            contrib += 0.5f * vv * vv;
        else if (col == KDIM)      contrib += vv;
      }
      contrib += __shfl_xor(contrib, 1);
      contrib += __shfl_xor(contrib, 2);
      contrib += __shfl_xor(contrib, 4);
      contrib += __shfl_xor(contrib, 8);
      if (lr == 0) atomicAdd(&augp[wm + fm * 16 + cq * 4 + r], contrib);
    }
  }
  __syncthreads();
  if (t < 64) {
    float z = arg[m0 + t] + augp[t] + b[0];
    out[m0 + t] = 1.f / (1.f + __expf(-z));
  }
}

extern "C" void kernel_launch(void* const* d_in, const int* in_sizes, int n_in,
                              void* d_out, int out_size, void* d_ws, size_t ws_size,
                              hipStream_t stream) {
  const float* x = (const float*)d_in[0];   // [16384, 2048]
  const float* w = (const float*)d_in[1];   // [2048]
  const float* b = (const float*)d_in[2];   // scalar
  const float* v = (const float*)d_in[3];   // [2048, 32, 64]
  float* out = (float*)d_out;               // [16384] fp32

  char* ws = (char*)d_ws;
  _Float16* xh  = (_Float16*)ws;                          // 67,108,864 B
  _Float16* vt  = (_Float16*)(ws + 67108864);             //  8,912,896 B
  float*    arg = (float*)(ws + 67108864 + 8912896);      //     65,536 B

  k_prep_x<<<8192, 256, 0, stream>>>(x, xh);
  k_prep_v<<<2112, 256, 0, stream>>>(v, w, vt, arg);
  k_gemm<<<512, 512, 0, stream>>>(xh, vt, arg);
  k_fin_aug<<<256, 256, 0, stream>>>(xh, vt, arg, b, out);
}

// Round 9
// 354.886 us; speedup vs baseline: 6.3150x; 1.0559x over previous
//
#include <hip/hip_runtime.h>
#include <cstdint>
#include <cstddef>

// Problem constants
#define B_ROWS 16384
#define FEAT   2048
#define FIELD  32
#define KDIM   64
#define NCOLS  2048           // FIELD*KDIM (main quadratic columns)
#define NAUG   2176           // 2048 + 64 (vsum) + 1 (w) + 63 zero-pad

using half8   = __attribute__((ext_vector_type(8))) _Float16;
using half4   = __attribute__((ext_vector_type(4))) _Float16;
using floatx4 = __attribute__((ext_vector_type(4))) float;

// Async global->LDS, 16B per lane. LDS dest must be wave-uniform base + lane*16.
__device__ __forceinline__ void load_lds16(const void* g, void* l) {
  __builtin_amdgcn_global_load_lds((const __attribute__((address_space(1))) void*)g,
                                   (__attribute__((address_space(3))) void*)l, 16, 0, 0);
}

// --- prep A: v transpose + vsum + w/zero rows + arg zero (runs FIRST) ------
__global__ __launch_bounds__(256) void k_prep_v(const float* __restrict__ v,
                                                const float* __restrict__ w,
                                                _Float16* __restrict__ vt,
                                                float* __restrict__ arg) {
  const int bb = blockIdx.x;
  const int t = threadIdx.x;
  if (bb < 1024) {
    __shared__ _Float16 tile[64 * 68];
    const int f0 = (bb >> 5) * 64;
    const int n0 = (bb & 31) * 64;
#pragma unroll
    for (int j = 0; j < 4; ++j) {
      int c = j * 256 + t;
      int row = c >> 4;                           // f local
      int col = (c & 15) * 4;                     // n local
      float4 val = *(const float4*)(v + (size_t)(f0 + row) * NCOLS + n0 + col);
      tile[row * 68 + col + 0] = (_Float16)val.x;
      tile[row * 68 + col + 1] = (_Float16)val.y;
      tile[row * 68 + col + 2] = (_Float16)val.z;
      tile[row * 68 + col + 3] = (_Float16)val.w;
    }
    __syncthreads();
#pragma unroll
    for (int j = 0; j < 4; ++j) {
      int c = j * 256 + t;
      int nl = c >> 4;                            // n local (row of vt)
      int fl = (c & 15) * 4;                      // f local group of 4
      half4 h = { tile[(fl + 0) * 68 + nl], tile[(fl + 1) * 68 + nl],
                  tile[(fl + 2) * 68 + nl], tile[(fl + 3) * 68 + nl] };
      *(half4*)(vt + (size_t)(n0 + nl) * FEAT + f0 + fl) = h;
    }
  } else if (bb < 1536) {
    const int k = t & 63;
    const int f = (bb - 1024) * 4 + (t >> 6);
    float s = 0.f;
#pragma unroll
    for (int si = 0; si < FIELD; ++si) s += v[(size_t)f * NCOLS + si * KDIM + k];
    vt[(size_t)(NCOLS + k) * FEAT + f] = (_Float16)s;
  } else if (bb < 2048) {
    int idx = (bb - 1536) * 256 + t;              // 64*2048 elements
    int r = NCOLS + KDIM + (idx >> 11);           // 2112..2175
    int f = idx & 2047;
    vt[(size_t)r * FEAT + f] = (r == NCOLS + KDIM) ? (_Float16)w[f] : (_Float16)0.f;
  } else {
    arg[(bb - 2048) * 256 + t] = 0.f;
  }
}

// --- prep B: x fp32 -> xh fp16 FUSED with the aug thin-GEMM ----------------
// R9: while converting x (the data is already in registers), also compute
// the aug contribution  aug[m] = sum_{k<64} 0.5*s_k^2 + x.w  against vt rows
// 2048..2175 (0..63 vsum -> +0.5c^2, 64 -> +c (w), 65..127 zero) and
// atomicAdd it into arg (zeroed by k_prep_v; gemm's -0.5c^2 atomics combine
// order-free). Kills the old fin_aug kernel and its 67MB xh re-read.
// 512 blocks x 32 rows. A: fp32 load -> cvt -> xh store (linear) + LDS
// store to XOR-swizzled dest (reg-staging; write & read use the same XOR).
// B: gload_lds with pre-swizzled source (R8-verified pattern), L2-hot.
__global__ __launch_bounds__(256) void k_prep_xa(const float* __restrict__ x,
                                                 const _Float16* __restrict__ vt,
                                                 _Float16* __restrict__ xh,
                                                 float* __restrict__ arg) {
  __shared__ __align__(16) _Float16 lds_a[32 * 64];
  __shared__ __align__(16) _Float16 lds_b[128 * 64];
  const int t = threadIdx.x;
  const int m0 = blockIdx.x * 32;
  const int lane = t & 63;
  const int wave = t >> 6;
  const int wm = (wave & 1) * 16;               // M offset (1 frag row)
  const int wn = (wave >> 1) * 64;              // N offset (4 frag cols)
  const int lr = lane & 15;
  const int lk = (lane >> 4) * 8;

  // A staging ids: one 16B chunk per thread (32 rows x 8 kc = 256 chunks).
  const int arow = t >> 3;
  const int akc  = t & 7;
  const float*    xsrc = x  + (size_t)(m0 + arow) * FEAT + akc * 8;
  _Float16*       xdst = xh + (size_t)(m0 + arow) * FEAT + akc * 8;
  _Float16*       adst = lds_a + arow * 64 + (akc ^ (arow & 7)) * 8;

  floatx4 acc[4] = {};

  for (int k0 = 0; k0 < FEAT; k0 += 64) {
    float4 va = *(const float4*)(xsrc + k0);
    float4 vb = *(const float4*)(xsrc + k0 + 4);
    half8 h = { (_Float16)va.x, (_Float16)va.y, (_Float16)va.z, (_Float16)va.w,
                (_Float16)vb.x, (_Float16)vb.y, (_Float16)vb.z, (_Float16)vb.w };
    *(half8*)(xdst + k0) = h;                   // xh for the main gemm
    *(half8*)adst = h;                          // swizzled LDS A-tile
    // B tile: vt aug rows 2048..2175 (128x64), XOR-swizzled gload_lds.
#pragma unroll
    for (int i = 0; i < 4; ++i) {
      int c = i * 256 + t;                      // 0..1023
      int row = c >> 3;
      int g = (c & 7) ^ (row & 7);
      load_lds16(vt + (size_t)(NCOLS + row) * FEAT + k0 + g * 8, lds_b + c * 8);
    }
    __syncthreads();
#pragma unroll
    for (int ks = 0; ks < 64; ks += 32) {
      const int kc = (ks + lk) >> 3;
      const int ma = wm + lr;
      half8 af = *(const half8*)(lds_a + ma * 64 + (kc ^ (ma & 7)) * 8);
      half8 bf[4];
#pragma unroll
      for (int f = 0; f < 4; ++f) {
        int nb = wn + f * 16 + lr;
        bf[f] = *(const half8*)(lds_b + nb * 64 + (kc ^ (nb & 7)) * 8);
      }
#pragma unroll
      for (int fn = 0; fn < 4; ++fn)
        acc[fn] = __builtin_amdgcn_mfma_f32_16x16x32_f16(af, bf[fn],
                                                         acc[fn], 0, 0, 0);
    }
    __syncthreads();
  }

  // Epilogue: C/D layout col=lane&15, row=(lane>>4)*4+reg.
  const int cq = lane >> 4;
#pragma unroll
  for (int r = 0; r < 4; ++r) {
    float contrib = 0.f;
#pragma unroll
    for (int fn = 0; fn < 4; ++fn) {
      int col = wn + fn * 16 + lr;
      float vv = acc[fn][r];
      if (col < KDIM)            contrib += 0.5f * vv * vv;
      else if (col == KDIM)      contrib += vv;
    }
    contrib += __shfl_xor(contrib, 1);
    contrib += __shfl_xor(contrib, 2);
    contrib += __shfl_xor(contrib, 4);
    contrib += __shfl_xor(contrib, 8);
    if (lr == 0) atomicAdd(&arg[m0 + wm + cq * 4 + r], contrib);
  }
}

// --- main GEMM (cols 0..2047 only) + row-reduce epilogue -------------------
// R8-verified (135us, MfmaUtil 46, prediction matched twice) -- FROZEN.
// Grid 512 = 64m x 8n = exactly 2 blocks/CU, zero tail; XCD swizzle 512 =
// 8*64 bijective, 2-n-group decode -> 2MB B L2-resident per XCD.
__global__ __launch_bounds__(512, 2) void k_gemm(const _Float16* __restrict__ xh,
                                                 const _Float16* __restrict__ vt,
                                                 float* __restrict__ arg) {
  __shared__ __align__(16) _Float16 lds[65536];   // 128 KiB
  const int tid  = threadIdx.x;
  const int lane = tid & 63;
  const int wave = tid >> 6;      // 0..7
  const int wm   = wave >> 2;     // 0..1 -> M offset wm*128
  const int wn   = wave & 3;      // 0..3 -> N offset wn*64
  const int lr   = lane & 15;     // frag row (A) / col (B)
  const int q    = lane >> 4;     // k-chunk within 32-k granule

  const int bid = blockIdx.x;
  const int wg  = (bid & 7) * 64 + (bid >> 3);
  const int ng  = wg >> 7;
  const int rem = wg & 127;
  const int mi  = rem >> 1;
  const int nr  = rem & 1;
  const int m0  = mi * 256;
  const int n0  = (ng * 2 + nr) * 256;           // 0..1792

  int offA[4], offB[4];
#pragma unroll
  for (int f = 0; f < 4; ++f) {
    int L = f * 16 + lr;
    int u = wm * 4 + q;
    offA[f] = L * 64 + ((u ^ (L & 7)) * 8);
  }
#pragma unroll
  for (int g = 0; g < 4; ++g) {
    int L = (wn & 1) * 64 + g * 16 + lr;
    int u = (wn >> 1) * 4 + q;
    offB[g] = L * 64 + ((u ^ (L & 7)) * 8);
  }

  const int L0   = tid >> 3;
  const int u0   = (tid & 7) ^ (L0 & 7);
  const int row0 = (u0 >> 2) * 128 + L0;
  const int kc0  = u0 & 3;
  const _Float16* pA0 = xh + (size_t)(m0 + row0) * FEAT + kc0 * 8;
  const _Float16* pA1 = pA0 + (size_t)64 * FEAT;
  const _Float16* pB0 = vt + (size_t)(n0 + row0) * FEAT + kc0 * 8;  // rows < 2048
  const _Float16* pB1 = pB0 + (size_t)64 * FEAT;

  auto stageA = [&](int koff, int seg) {
    load_lds16(pA0 + koff, lds + seg + tid * 8);
    load_lds16(pA1 + koff, lds + seg + 4096 + tid * 8);
  };
  auto stageB = [&](int koff, int seg) {
    load_lds16(pB0 + koff, lds + seg + tid * 8);
    load_lds16(pB1 + koff, lds + seg + 4096 + tid * 8);
  };

  floatx4 acc[8][4] = {};
  half8 af[4], bf[4];

  stageA(0, 0);       stageB(0, 32768);
  stageA(32, 8192);   stageB(32, 40960);
  stageA(64, 16384);  stageB(64, 49152);
  asm volatile("s_waitcnt vmcnt(4)" ::: "memory");  // K-tile 0 fully landed
  __builtin_amdgcn_s_barrier();

#define PHASE_TAIL()                                        \
    __builtin_amdgcn_s_barrier();                           \
    asm volatile("s_waitcnt lgkmcnt(0)" ::: "memory");      \
    __builtin_amdgcn_sched_barrier(0);                      \
    __builtin_amdgcn_s_setprio(1)

#define PHASE_END()                                         \
    __builtin_amdgcn_s_setprio(0);                          \
    __builtin_amdgcn_s_barrier()

#pragma unroll 2
  for (int t = 0; t < 32; ++t) {
    const int sA0  = ((t & 1) << 1) * 8192;                 // segA(buf, kg0)
    const int sB0  = 32768 + sA0;                           // segB(buf, kg0)
    const int sPA1 = ((((t + 1) & 1) << 1) | 1) * 8192;     // segA(buf^1, kg1)

    // ---- phase 0: ks=0, M-frags 0-3 ---------------------------------------
#pragma unroll
    for (int g = 0; g < 4; ++g) bf[g] = *(const half8*)(lds + sB0 + offB[g]);
#pragma unroll
    for (int f = 0; f < 4; ++f) af[f] = *(const half8*)(lds + sA0 + offA[f]);
    if (t < 31) stageA((t + 1) * 64 + 32, sPA1);
    PHASE_TAIL();
#pragma unroll
    for (int f = 0; f < 4; ++f)
#pragma unroll
      for (int g = 0; g < 4; ++g)
        acc[f][g] = __builtin_amdgcn_mfma_f32_16x16x32_f16(af[f], bf[g],
                                                           acc[f][g], 0, 0, 0);
    PHASE_END();

    // ---- phase 1: ks=0, M-frags 4-7 (bf reused) ---------------------------
#pragma unroll
    for (int f = 0; f < 4; ++f) af[f] = *(const half8*)(lds + sA0 + 4096 + offA[f]);
    if (t < 31) stageB((t + 1) * 64 + 32, 32768 + sPA1);
    PHASE_TAIL();
#pragma unroll
    for (int f = 0; f < 4; ++f)
#pragma unroll
      for (int g = 0; g < 4; ++g)
        acc[4 + f][g] = __builtin_amdgcn_mfma_f32_16x16x32_f16(af[f], bf[g],
                                                               acc[4 + f][g], 0, 0, 0);
    PHASE_END();

    // ---- phase 2: ks=32, M-frags 0-3 --------------------------------------
#pragma unroll
    for (int g = 0; g < 4; ++g) bf[g] = *(const half8*)(lds + sB0 + 8192 + offB[g]);
#pragma unroll
    for (int f = 0; f < 4; ++f) af[f] = *(const half8*)(lds + sA0 + 8192 + offA[f]);
    if (t < 30) stageA((t + 2) * 64, sA0);
    PHASE_TAIL();
#pragma unroll
    for (int f = 0; f < 4; ++f)
#pragma unroll
      for (int g = 0; g < 4; ++g)
        acc[f][g] = __builtin_amdgcn_mfma_f32_16x16x32_f16(af[f], bf[g],
                                                           acc[f][g], 0, 0, 0);
    PHASE_END();

    // ---- phase 3: ks=32, M-frags 4-7 + per-K-tile counted vmcnt -----------
#pragma unroll
    for (int f = 0; f < 4; ++f) af[f] = *(const half8*)(lds + sA0 + 12288 + offA[f]);
    if (t < 30) stageB((t + 2) * 64, sB0);
    __builtin_amdgcn_s_barrier();
    asm volatile("s_waitcnt lgkmcnt(0)" ::: "memory");
    __builtin_amdgcn_sched_barrier(0);
    __builtin_amdgcn_s_setprio(1);
#pragma unroll
    for (int f = 0; f < 4; ++f)
#pragma unroll
      for (int g = 0; g < 4; ++g)
        acc[4 + f][g] = __builtin_amdgcn_mfma_f32_16x16x32_f16(af[f], bf[g],
                                                               acc[4 + f][g], 0, 0, 0);
    __builtin_amdgcn_s_setprio(0);
    if (t < 30) { asm volatile("s_waitcnt vmcnt(4)" ::: "memory"); }
    else        { asm volatile("s_waitcnt vmcnt(0)" ::: "memory"); }
    __builtin_amdgcn_sched_barrier(0);
    __builtin_amdgcn_s_barrier();
  }
#undef PHASE_TAIL
#undef PHASE_END

  // Epilogue: all cols < 2048 -> coeff uniformly -0.5*c^2.
  const int cq = lane >> 4;
  const int mrow = m0 + wm * 128;
#pragma unroll
  for (int f = 0; f < 8; ++f) {
#pragma unroll
    for (int r = 0; r < 4; ++r) {
      float contrib = 0.f;
#pragma unroll
      for (int g = 0; g < 4; ++g) {
        float vv = acc[f][g][r];
        contrib -= 0.5f * vv * vv;
      }
      contrib += __shfl_xor(contrib, 1);
      contrib += __shfl_xor(contrib, 2);
      contrib += __shfl_xor(contrib, 4);
      contrib += __shfl_xor(contrib, 8);
      if (lr == 0) atomicAdd(&arg[mrow + f * 16 + cq * 4 + r], contrib);
    }
  }
}

// --- finalize: sigmoid ------------------------------------------------------
__global__ __launch_bounds__(256) void k_fin(const float* __restrict__ arg,
                                             const float* __restrict__ b,
                                             float* __restrict__ out) {
  int i = blockIdx.x * 256 + threadIdx.x;
  float z = arg[i] + b[0];
  out[i] = 1.f / (1.f + __expf(-z));
}

extern "C" void kernel_launch(void* const* d_in, const int* in_sizes, int n_in,
                              void* d_out, int out_size, void* d_ws, size_t ws_size,
                              hipStream_t stream) {
  const float* x = (const float*)d_in[0];   // [16384, 2048]
  const float* w = (const float*)d_in[1];   // [2048]
  const float* b = (const float*)d_in[2];   // scalar
  const float* v = (const float*)d_in[3];   // [2048, 32, 64]
  float* out = (float*)d_out;               // [16384] fp32

  char* ws = (char*)d_ws;
  _Float16* xh  = (_Float16*)ws;                          // 67,108,864 B
  _Float16* vt  = (_Float16*)(ws + 67108864);             //  8,912,896 B
  float*    arg = (float*)(ws + 67108864 + 8912896);      //     65,536 B

  k_prep_v<<<2112, 256, 0, stream>>>(v, w, vt, arg);
  k_prep_xa<<<512, 256, 0, stream>>>(x, vt, xh, arg);
  k_gemm<<<512, 512, 0, stream>>>(xh, vt, arg);
  k_fin<<<64, 256, 0, stream>>>(arg, b, out);
}